// Round 9
// baseline (1720.134 us; speedup 1.0000x reference)
//
#include <hip/hip_runtime.h>

// GPUHungarianMatcher R16c — identical source to R16b (round-8 bench was an
// infrastructure failure: "MI355X container failed twice"; no data).
//
// R16 = DUAL-CHAIN INTERLEAVE: one block (4 waves) processes TWO batches
// (independent Hungarian chains A and B) in lockstep supersteps:
//      pre(cA); pre(cB); __syncthreads(); post(cA); post(cB);
// Rationale (R12-R15 evidence): the single-chain spine is latency-bound at
// ~33% issue occupancy; per-step stalls (~570cy of 850) are many small
// dependency gaps (DPP chain, mailbox read ~130cy, drains) that no local
// reordering closes. A second INDEPENDENT chain's issue work fills those
// stalls: the compiler interleaves two disjoint register sets freely, the
// two chains' mailbox-read latencies overlap, and ONE barrier serves two
// steps. Expected superstep ~650-750cy for TWO steps vs 2x850 today.
//
// Chain bodies are R15's validated code verbatim (absmax-0 lineage):
//  * pre  (STEP): record, scan (+inf f32 poison), fmin-tree argmin + ==-mask
//    + ctz, per-lane myCd = colDat[own bidx] (off-chain), monotone u64 key,
//    DPP wave-min + ballot (+ exact-tie slow path), winning lane writes the
//    32B mailbox {khi,klo,bidx | u_lo,u_hi,tx,ty}.
//  * post (STEP): 8 independent uniform b128 mailbox reads, pairwise
//    tournament (left wins ties == left-to-right scan), u32-domain cd fold,
//    D += decoded delta, usedMask/recCol updates, break check.
//  * EPI rows (S>1): scatter (p/colDat/vdelta) in pre, apply (vreg -= slot,
//    reset) in post — the old F barrier is the superstep barrier.
//  * S==1 rows: owner-thread writes colDat/p in post, no epilogue superstep
//    (R15 fast path; owner-read-own-column makes it race-free).
//
// Interleaving-correctness (all R15 proofs carry over):
//  * modes/break decisions are computed from identical folded data on every
//    thread => block-uniform => the single barrier per superstep is uniform.
//  * chains touch DISJOINT LDS arrays (colDat/p/pk2/vdelta/rowTgt/ansArr
//    indexed by chain id) — no cross-chain hazards.
//  * mailbox parity per chain toggles per STEP superstep; any read -> next
//    same-parity write spans >= 1 superstep barrier.
//  * vdelta reset (post) vs next scatter (pre, >= next row's first STEP
//    superstep later) spans >= 1 barrier.
//  * S==1 owner colDat write (post t) vs myCd reads (pre t+1): only the
//    owner reads its own column => same-thread order; p[j1] reads happen in
//    post(t+1), after BAR(t+1).
// colDat PADDED index j + (j>>8) (array Q+9) — spreads the bk*4096B
// component of the per-lane myCd read across banks (R14's 214K conflict
// cycles). Pure layout change, applied at every colDat site.
//
// Exactness invariants (unchanged): cost fp32 fabsf+fabsf+np, reduced fp64
// ((double)cf-u)-v; scans read only pre-search u/v; argmin = np.argmin
// first-occurrence; tournament lexicographic (key, idx); u update = single
// add of prefix-difference; v update = vdelta scatter (bitwise-identical
// values); softmax bitwise-identical R2 tree per chain (mapping unchanged:
// NT=256, j = 1 + tid + k*256); free-flag tx = -1.0f.

constexpr int B = 8;
constexpr int Q = 2048;        // columns (queries)
constexpr int T = 256;         // rows (targets)
constexpr int NT = 256;        // threads per block (4 waves)
constexpr int KPT = Q / NT;    // 8 columns per thread, j = 1 + tid + k*256
constexpr int NW = NT / 64;

struct __align__(16) CD { double u; float tx, ty; };   // one ds_read_b128

__device__ __forceinline__ unsigned wave_min_u32_dpp(unsigned a) {
  // full-wave u32 min: row_shr 1,2,4,8 then row_bcast15, row_bcast31;
  // invalid source lanes keep old (bound_ctrl=false, masks 0xf) = identity.
  int v = (int)a, t;
  t = __builtin_amdgcn_update_dpp(v, v, 0x111, 0xf, 0xf, false);
  v = ((unsigned)t < (unsigned)v) ? t : v;
  t = __builtin_amdgcn_update_dpp(v, v, 0x112, 0xf, 0xf, false);
  v = ((unsigned)t < (unsigned)v) ? t : v;
  t = __builtin_amdgcn_update_dpp(v, v, 0x114, 0xf, 0xf, false);
  v = ((unsigned)t < (unsigned)v) ? t : v;
  t = __builtin_amdgcn_update_dpp(v, v, 0x118, 0xf, 0xf, false);
  v = ((unsigned)t < (unsigned)v) ? t : v;
  t = __builtin_amdgcn_update_dpp(v, v, 0x142, 0xf, 0xf, false);
  v = ((unsigned)t < (unsigned)v) ? t : v;
  t = __builtin_amdgcn_update_dpp(v, v, 0x143, 0xf, 0xf, false);
  v = ((unsigned)t < (unsigned)v) ? t : v;
  return (unsigned)__builtin_amdgcn_readlane(v, 63);   // lane 63 = global min
}

// Per-chain register state. Arrays indexed ONLY by unrolled compile-time
// constants (rule #20: no dynamic register indexing).
struct CH {
  float qx[KPT], qy[KPT], np_[KPT];
  double vreg[KPT];
  int i, mode;               // mode: 0 = STEP, 1 = EPI, 2 = DONE
  unsigned usedMask;
  double D, ui0;
  float tX, tY;
  int s, S, i0, j1v;
  int recRow, recCol, recPrev;
  double recU, recD;
  float recTX, recTY;
  int par, cpar;
};

__launch_bounds__(NT, 1)
__global__ void hungarian_r16(const float* __restrict__ outs,
                              const float* __restrict__ tgts,
                              int* __restrict__ out) {
  const int tid = threadIdx.x;
  const int lane = tid & 63;
  const int wv = tid >> 6;

  __shared__ CD colDat[2][Q + 9];     // PADDED: slot j + (j>>8)
  __shared__ float2 rowTgt[2][T + 1]; // read-only after init
  __shared__ short p[2][Q + 1];       // p[j]: row matched to col j, 0 free
  __shared__ uint4 pk2[2][2][NW][2];  // [chain][parity][wave][key|cd]
  __shared__ double vdelta[2][Q];     // v-delta scatter; 0.0 = no update
  __shared__ int ansArr[2][T];
  __shared__ double s_rv[NW];
  __shared__ float sh_f;

  const float FINF = __int_as_float(0x7f800000);   // +inf poison

  CH cA, cB;

  // ---- per-chain staging + softmax (bitwise-identical R2 tree) + init ----
  auto initChain = [&](CH& c, const int ci, const int bat) {
    const size_t qbase = (size_t)bat * Q;
    const size_t tbase = (size_t)bat * T;
    float xs[KPT];
#pragma unroll
    for (int k = 0; k < KPT; ++k) {
      const size_t o = (qbase + tid + k * NT) * 3;
      xs[k] = outs[o];
      c.qx[k] = outs[o + 1];
      c.qy[k] = outs[o + 2];
    }
    {
      const size_t o = (tbase + tid) * 3;   // T == NT: one target per thread
      rowTgt[ci][tid + 1] = make_float2(tgts[o + 1], tgts[o + 2]);
      if (tid == 0) rowTgt[ci][0] = make_float2(0.f, 0.f);
    }
    float lmax = xs[0];
#pragma unroll
    for (int k = 1; k < KPT; ++k) lmax = fmaxf(lmax, xs[k]);
    for (int off = 32; off > 0; off >>= 1) lmax = fmaxf(lmax, __shfl_down(lmax, off));
    if ((tid & 63) == 0) s_rv[tid >> 6] = (double)lmax;
    __syncthreads();
    if (tid == 0) {
      float m2 = (float)s_rv[0];
      for (int w = 1; w < NW; ++w) m2 = fmaxf(m2, (float)s_rv[w]);
      sh_f = m2;
    }
    __syncthreads();
    const float smax = sh_f;
    float ex[KPT];
    float lsum = 0.f;
#pragma unroll
    for (int k = 0; k < KPT; ++k) { ex[k] = expf(xs[k] - smax); lsum += ex[k]; }
    for (int off = 32; off > 0; off >>= 1) lsum += __shfl_down(lsum, off);
    if ((tid & 63) == 0) s_rv[tid >> 6] = (double)lsum;
    __syncthreads();
    if (tid == 0) {
      float s2 = 0.f;
      for (int w = 0; w < NW; ++w) s2 += (float)s_rv[w];
      sh_f = s2;
    }
    __syncthreads();
    const float ssum = sh_f;
#pragma unroll
    for (int k = 0; k < KPT; ++k) c.np_[k] = -(ex[k] / ssum);

    for (int j = tid; j <= Q; j += NT) {
      p[ci][j] = 0;
      CD c0; c0.u = 0.0; c0.tx = -1.0f; c0.ty = 0.0f;   // all columns free
      colDat[ci][j + (j >> 8)] = c0;
    }
#pragma unroll
    for (int k = 0; k < KPT; ++k) {
      c.vreg[k] = 0.0;
      vdelta[ci][tid + (k << 8)] = 0.0;
    }
    c.par = 0; c.cpar = 0;
    __syncthreads();              // rowTgt/colDat/p/vdelta visible
    c.i = 1; c.mode = 0; c.usedMask = 0; c.D = 0.0; c.i0 = 1; c.ui0 = 0.0;
    const float2 t0 = rowTgt[ci][1];
    c.tX = t0.x; c.tY = t0.y;
    c.s = 0; c.S = 0; c.j1v = 0;
    c.recRow = 0; c.recCol = 0; c.recPrev = 0;
    c.recU = 0.0; c.recD = 0.0; c.recTX = 0.f; c.recTY = 0.f;
  };

  // ---- row advance (uniform; called in post phases) ----
  auto advance_row = [&](CH& c, const int ci) {
    c.i += 1;
    if (c.i > T) { c.mode = 2; return; }
    c.mode = 0;
    c.usedMask = 0; c.D = 0.0; c.i0 = c.i; c.ui0 = 0.0;  // u[i]==0 at row start
    const float2 tt = rowTgt[ci][c.i];   // read-only; latency hides into pre
    c.tX = tt.x; c.tY = tt.y;
    c.s = 0; c.j1v = 0;
  };

  // ---- STEP pre-barrier phase (R15 body, parameterized) ----
  auto step_pre = [&](CH& c, const int ci) {
    c.cpar = c.par; c.par ^= 1;
    if (tid == c.s) {
      c.recRow = c.i0; c.recU = c.ui0; c.recTX = c.tX; c.recTY = c.tY;
      c.recD = c.D; c.recPrev = c.j1v;
    }
    double cv[KPT];
#pragma unroll
    for (int k = 0; k < KPT; ++k) {
      float cf = fabsf(c.qx[k] - c.tX) + fabsf(c.qy[k] - c.tY) + c.np_[k];
      if (c.usedMask & (1u << k)) cf = FINF;
      cv[k] = ((double)cf - c.ui0) - c.vreg[k];
    }
    const double m01 = fmin(cv[0], cv[1]), m23 = fmin(cv[2], cv[3]);
    const double m45 = fmin(cv[4], cv[5]), m67 = fmin(cv[6], cv[7]);
    const double m03 = fmin(m01, m23), m47 = fmin(m45, m67);
    double bval = fmin(m03, m47);
    unsigned emsk = 0;
#pragma unroll
    for (int k = 0; k < KPT; ++k) emsk |= (cv[k] == bval) ? (1u << k) : 0u;
    const int bk = (int)__builtin_ctz(emsk);   // emsk != 0 always
    int bidx = 1 + tid + (bk << 8);

    // pre-barrier owner-read of MY candidate's colDat (padded index)
    const CD myCd = colDat[ci][bidx + (bidx >> 8)];

    bval += 0.0;   // canonicalize -0 -> +0
    const long long bb = __double_as_longlong(bval);
    const unsigned long long key = (unsigned long long)bb ^
        ((bb < 0) ? 0xFFFFFFFFFFFFFFFFull : 0x8000000000000000ull);
    const unsigned khi = (unsigned)(key >> 32);
    const unsigned klo = (unsigned)key;

    const unsigned minhi = wave_min_u32_dpp(khi);
    const unsigned long long mask = __ballot(khi == minhi);
    int wl;
    if (__popcll(mask) == 1) {
      wl = (int)__ffsll(mask) - 1;
    } else {
      unsigned wklo = 0xffffffffu; int widx = 0x7fffffff; wl = 0;
      unsigned long long mm = mask;
      while (mm) {
        const int l = (int)__ffsll(mm) - 1; mm &= mm - 1;
        const unsigned lo2 = (unsigned)__builtin_amdgcn_readlane((int)klo, l);
        const int ix2 = __builtin_amdgcn_readlane(bidx, l);
        if (lo2 < wklo || (lo2 == wklo && ix2 < widx)) {
          wklo = lo2; widx = ix2; wl = l;
        }
      }
    }
    if (lane == wl) {
      pk2[ci][c.cpar][wv][0] = make_uint4(minhi, klo, (unsigned)bidx, 0u);
      const unsigned long long cu =
          (unsigned long long)__double_as_longlong(myCd.u);
      pk2[ci][c.cpar][wv][1] = make_uint4((unsigned)cu, (unsigned)(cu >> 32),
                                          __float_as_uint(myCd.tx),
                                          __float_as_uint(myCd.ty));
    }
  };

  // ---- STEP post-barrier phase (fold + update + break handling) ----
  auto step_post = [&](CH& c, const int ci) {
    const int cpar = c.cpar;
    const uint4 c0v = pk2[ci][cpar][0][0];
    const uint4 c1v = pk2[ci][cpar][1][0];
    const uint4 c2v = pk2[ci][cpar][2][0];
    const uint4 c3v = pk2[ci][cpar][3][0];
    const uint4 d0v = pk2[ci][cpar][0][1];
    const uint4 d1v = pk2[ci][cpar][1][1];
    const uint4 d2v = pk2[ci][cpar][2][1];
    const uint4 d3v = pk2[ci][cpar][3][1];

    const unsigned long long k0b = ((unsigned long long)c0v.x << 32) | c0v.y;
    const unsigned long long k1b = ((unsigned long long)c1v.x << 32) | c1v.y;
    const unsigned long long k2b = ((unsigned long long)c2v.x << 32) | c2v.y;
    const unsigned long long k3b = ((unsigned long long)c3v.x << 32) | c3v.y;
    const int j0b = (int)c0v.z, j1bb = (int)c1v.z;
    const int j2b = (int)c2v.z, j3b = (int)c3v.z;
    const bool w01 = (k1b < k0b) || (k1b == k0b && j1bb < j0b);
    const unsigned long long k01 = w01 ? k1b : k0b;
    const int j01 = w01 ? j1bb : j0b;
    const bool w23 = (k3b < k2b) || (k3b == k2b && j3b < j2b);
    const unsigned long long k23 = w23 ? k3b : k2b;
    const int j23 = w23 ? j3b : j2b;
    const bool wf = (k23 < k01) || (k23 == k01 && j23 < j01);
    const unsigned long long bkk = wf ? k23 : k01;
    const int j1 = wf ? j23 : j01;          // selected column, 1-based
    const unsigned ulA = w01 ? d1v.x : d0v.x, uhA = w01 ? d1v.y : d0v.y;
    const unsigned xAf = w01 ? d1v.z : d0v.z, yAf = w01 ? d1v.w : d0v.w;
    const unsigned ulB = w23 ? d3v.x : d2v.x, uhB = w23 ? d3v.y : d2v.y;
    const unsigned xBf = w23 ? d3v.z : d2v.z, yBf = w23 ? d3v.w : d2v.w;
    const unsigned ulW = wf ? ulB : ulA, uhW = wf ? uhB : uhA;
    const unsigned xW = wf ? xBf : xAf, yW = wf ? yBf : yAf;
    const double cdun = __longlong_as_double(
        (long long)(((unsigned long long)uhW << 32) | ulW));
    const float cdtx = __uint_as_float(xW);
    const float cdty = __uint_as_float(yW);

    const long long db = (long long)((bkk & 0x8000000000000000ull)
                                         ? (bkk ^ 0x8000000000000000ull) : ~bkk);
    c.D += __longlong_as_double(db);
    if (tid == ((j1 - 1) & 255)) c.usedMask |= 1u << ((j1 - 1) >> 8);
    if (tid == c.s) c.recCol = j1;
    const int pj1 = (int)p[ci][j1];   // off-path: feeds next pre's recorder
    c.j1v = j1;
    ++c.s;
    if (cdtx < 0.0f) {               // free column => path complete
      c.S = c.s;
      if (c.S == 1) {
        // fast path: unew = 0 + (D - 0) = D bitwise; tX/tY = row i's target.
        // Owner writes its own colDat (owner-only pre-barrier reader) + p
        // (others read p only post-next-barrier).
        const int jw = c.j1v;
        if (tid == ((jw - 1) & 255)) {
          p[ci][jw] = (short)c.i;
          CD c2; c2.u = c.D; c2.tx = c.tX; c2.ty = c.tY;
          colDat[ci][jw + (jw >> 8)] = c2;
        }
        advance_row(c, ci);
      } else {
        c.mode = 1;                  // epilogue superstep next
      }
    } else {
      c.ui0 = cdun; c.tX = cdtx; c.tY = cdty; c.i0 = pj1;
    }
  };

  // ---- EPI pre phase: scatter (old barrier F = this superstep's barrier) --
  auto epi_scatter = [&](CH& c, const int ci) {
    const double Dfin = c.D;
    if (tid < c.S) {
      p[ci][c.recCol] = (short)c.recRow;          // augment (rows/cols distinct)
      const double unew = c.recU + (Dfin - c.recD);
      CD c2; c2.u = unew; c2.tx = c.recTX; c2.ty = c.recTY;
      colDat[ci][c.recCol + (c.recCol >> 8)] = c2;
      if (tid >= 1) {
        // column of step tid-1 receives Dfin - recD (== serial-loop value);
        // path columns distinct => no collision
        vdelta[ci][c.recPrev - 1] = Dfin - c.recD;
      }
    }
  };

  // ---- EPI post phase: apply + reset, then advance ----
  auto epi_apply = [&](CH& c, const int ci) {
#pragma unroll
    for (int k = 0; k < KPT; ++k) {
      const double dv = vdelta[ci][tid + (k << 8)];
      c.vreg[k] -= dv;                 // 0.0 slots are bitwise no-ops
      vdelta[ci][tid + (k << 8)] = 0.0;
    }
    advance_row(c, ci);
  };

  initChain(cA, 0, 2 * blockIdx.x);
  initChain(cB, 1, 2 * blockIdx.x + 1);
  __syncthreads();

  // ---- superstep loop: two chains, one barrier ----
  while (cA.mode != 2 || cB.mode != 2) {
    if (cA.mode == 0) step_pre(cA, 0);
    else if (cA.mode == 1) epi_scatter(cA, 0);
    if (cB.mode == 0) step_pre(cB, 1);
    else if (cB.mode == 1) epi_scatter(cB, 1);
    __syncthreads();                  // the one barrier per superstep
    if (cA.mode == 0) step_post(cA, 0);
    else if (cA.mode == 1) epi_apply(cA, 0);
    if (cB.mode == 0) step_post(cB, 1);
    else if (cB.mode == 1) epi_apply(cB, 1);
  }
  __syncthreads();

  // ---- extract assignments, rank-sort (distinct values), write int32 ----
#pragma unroll
  for (int ci = 0; ci < 2; ++ci) {
    for (int j = 1 + tid; j <= Q; j += NT) {
      const int pi = (int)p[ci][j];
      if (pi > 0) ansArr[ci][pi - 1] = j - 1;
    }
  }
  __syncthreads();
#pragma unroll
  for (int ci = 0; ci < 2; ++ci) {
    const int bb = 2 * blockIdx.x + ci;
    const int a = ansArr[ci][tid];
    int rank = 0;
    for (int t2 = 0; t2 < T; ++t2) rank += (ansArr[ci][t2] < a) ? 1 : 0;
    out[(size_t)bb * T + rank] = a;                    // row_ind
    out[(size_t)B * T + (size_t)bb * T + rank] = tid;  // col_ind
  }
}

extern "C" void kernel_launch(void* const* d_in, const int* in_sizes, int n_in,
                              void* d_out, int out_size, void* d_ws, size_t ws_size,
                              hipStream_t stream) {
  const float* outs = (const float*)d_in[0];   // (8, 2048, 3) fp32
  const float* tgts = (const float*)d_in[1];   // (8, 256, 3) fp32
  int* out = (int*)d_out;                      // row_ind (8,256) ++ col_ind (8,256)
  hungarian_r16<<<B / 2, NT, 0, stream>>>(outs, tgts, out);
}

// Round 10
// 876.579 us; speedup vs baseline: 1.9623x; 1.9623x over previous
//
#include <hip/hip_runtime.h>

// GPUHungarianMatcher R17 — exact replication of the reference's degenerate
// "_lsa" (minv reset every inner iteration => chain-Dijkstra). One block
// (4 waves) per batch. R17 = R15 VERBATIM (best validated: 812us) + ONE
// isolated change: colDat index PADDING  j -> j + (j>>8)  (array Q+9).
//
// Hypothesis being tested (R14/R16 post-mortems): the per-lane pre-barrier
// myCd = colDat[bidx] read has bk*4096B per-lane offsets (4096 % 128 == 0)
// that stack all bk values on one bank set => up to 8-way serialization
// (SQ_LDS_BANK_CONFLICT 214K). The compiler emits s_waitcnt lgkmcnt(0)
// before every s_barrier (mailbox-write visibility), and lgkmcnt is a
// single in-order counter => the drain ALSO waits for the conflicted myCd
// reads — putting the conflict serialization on the critical path of every
// step. Padding (validated correct in the passing R16c) rotates the bank
// group with bk: byte addr = 16*(257*bk + tid + 1) => bank ~ 4*(bk+tid+1)
// mod 32. Injective: j = 256a+b (b<256) -> 257a+b; max 2056 <= Q+8.
//
// If dur drops ~40-60us: conflicts were exposed in the drain (R14's latency
// cut was real but masked). If dur is flat with conflicts collapsed: the
// ~850cy/step spine (scan issue + DPP + barrier drain + mailbox latency) is
// the structural floor of this decomposition.
//
// R15 recap (all validated, absmax-0 lineage R2-R15):
//  * mailbox-cd spine: per-lane owner reads its OWN candidate's colDat
//    pre-barrier (owner-read by construction — thread t only ever reads
//    columns 1+t+k*256), winning lane ships {keys|cd} through a 32B
//    mailbox, post-barrier = 8 independent uniform b128 reads + pairwise
//    tournament (left wins ties == left-to-right scan) + u32-domain cd fold.
//  * barrier E deleted (no post-barrier colDat reads; p race is on a dead
//    value); S==1 rows skip the epilogue entirely (owner writes colDat/p;
//    unew = 0+(D-0) = D bitwise); GLOBAL mailbox parity (toggles per step).
//  * epilogue (S>1): scatter p/colDat/vdelta from recorded registers;
//    barrier F; owners apply 8 static-index slots (0.0 = bitwise no-op).
//  * ui0 = 0 at row start (u[i] == 0 provably); rowTgt prefetched.
//  * argmin: fmin tree + ==-mask + ctz = np.argmin first occurrence; +inf
//    f32 poison for used columns; a wave can never be all-used.
//  * softmax bitwise-identical to the R2 tree (same thread mapping).
//  * free-flag: colDat[.].tx = -1.0f iff column unmatched (real tx >= 0).

constexpr int B = 8;
constexpr int Q = 2048;        // columns (queries)
constexpr int T = 256;         // rows (targets)
constexpr int NT = 256;        // threads per block (4 waves)
constexpr int KPT = Q / NT;    // 8 columns per thread, j = 1 + tid + k*256
constexpr int NW = NT / 64;

struct __align__(16) CD { double u; float tx, ty; };   // one ds_read_b128

__device__ __forceinline__ unsigned wave_min_u32_dpp(unsigned a) {
  // full-wave u32 min: row_shr 1,2,4,8 then row_bcast15, row_bcast31;
  // invalid source lanes keep old (bound_ctrl=false, masks 0xf) = identity.
  int v = (int)a, t;
  t = __builtin_amdgcn_update_dpp(v, v, 0x111, 0xf, 0xf, false);
  v = ((unsigned)t < (unsigned)v) ? t : v;
  t = __builtin_amdgcn_update_dpp(v, v, 0x112, 0xf, 0xf, false);
  v = ((unsigned)t < (unsigned)v) ? t : v;
  t = __builtin_amdgcn_update_dpp(v, v, 0x114, 0xf, 0xf, false);
  v = ((unsigned)t < (unsigned)v) ? t : v;
  t = __builtin_amdgcn_update_dpp(v, v, 0x118, 0xf, 0xf, false);
  v = ((unsigned)t < (unsigned)v) ? t : v;
  t = __builtin_amdgcn_update_dpp(v, v, 0x142, 0xf, 0xf, false);
  v = ((unsigned)t < (unsigned)v) ? t : v;
  t = __builtin_amdgcn_update_dpp(v, v, 0x143, 0xf, 0xf, false);
  v = ((unsigned)t < (unsigned)v) ? t : v;
  return (unsigned)__builtin_amdgcn_readlane(v, 63);   // lane 63 = global min
}

__launch_bounds__(NT, 1)
__global__ void hungarian_r17(const float* __restrict__ outs,
                              const float* __restrict__ tgts,
                              int* __restrict__ out) {
  const int b = blockIdx.x;
  const int tid = threadIdx.x;
  const int lane = tid & 63;
  const int wv = tid >> 6;

  __shared__ CD colDat[Q + 9];      // PADDED: slot j + (j>>8); tx = -1.0f free
  __shared__ float2 rowTgt[T + 1];  // rowTgt[r] = {tx[r-1], ty[r-1]} (read-only)
  __shared__ short p[Q + 1];        // p[j]: row matched to col j (1-based), 0 free
  __shared__ uint4 pk2[2][NW][2];   // mailbox (GLOBAL parity):
                                    //   [.][w][0] = {khi, klo, bidx, 0}
                                    //   [.][w][1] = {u_lo, u_hi, tx, ty}
  __shared__ double vdelta[Q];      // per-column v-delta scatter; 0.0 = no update
  __shared__ int ansArr[T];
  __shared__ double s_rv[NW];
  __shared__ float sh_f;

  const size_t qbase = (size_t)b * Q;
  const size_t tbase = (size_t)b * T;

  // ---- stage per-thread column data (fixed mapping j = 1 + tid + k*256) ----
  float xs[KPT], qx[KPT], qy[KPT];
#pragma unroll
  for (int k = 0; k < KPT; ++k) {
    const size_t o = (qbase + tid + k * NT) * 3;
    xs[k] = outs[o];
    qx[k] = outs[o + 1];
    qy[k] = outs[o + 2];
  }
  {
    const size_t o = (tbase + tid) * 3;   // T == NT: one target per thread
    rowTgt[tid + 1] = make_float2(tgts[o + 1], tgts[o + 2]);
    if (tid == 0) rowTgt[0] = make_float2(0.f, 0.f);
  }

  // ---- softmax over Q logits (bitwise-identical to the R2-passing tree) ----
  float lmax = xs[0];
#pragma unroll
  for (int k = 1; k < KPT; ++k) lmax = fmaxf(lmax, xs[k]);
  for (int off = 32; off > 0; off >>= 1) lmax = fmaxf(lmax, __shfl_down(lmax, off));
  if ((tid & 63) == 0) s_rv[tid >> 6] = (double)lmax;
  __syncthreads();
  if (tid == 0) {
    float m2 = (float)s_rv[0];
    for (int w = 1; w < NW; ++w) m2 = fmaxf(m2, (float)s_rv[w]);
    sh_f = m2;
  }
  __syncthreads();
  const float smax = sh_f;
  float ex[KPT];
  float lsum = 0.f;
#pragma unroll
  for (int k = 0; k < KPT; ++k) { ex[k] = expf(xs[k] - smax); lsum += ex[k]; }
  for (int off = 32; off > 0; off >>= 1) lsum += __shfl_down(lsum, off);
  if ((tid & 63) == 0) s_rv[tid >> 6] = (double)lsum;
  __syncthreads();
  if (tid == 0) {
    float s2 = 0.f;
    for (int w = 0; w < NW; ++w) s2 += (float)s_rv[w];
    sh_f = s2;
  }
  __syncthreads();
  const float ssum = sh_f;
  float np_[KPT];
#pragma unroll
  for (int k = 0; k < KPT; ++k) np_[k] = -(ex[k] / ssum);

  // ---- init state ----
  for (int j = tid; j <= Q; j += NT) {
    p[j] = 0;
    CD c0; c0.u = 0.0; c0.tx = -1.0f; c0.ty = 0.0f;   // all columns free
    colDat[j + (j >> 8)] = c0;
  }
  double vreg[KPT];   // v[j] for this thread's 8 columns (static indices only)
#pragma unroll
  for (int k = 0; k < KPT; ++k) {
    vreg[k] = 0.0;
    vdelta[tid + (k << 8)] = 0.0;
  }
  __syncthreads();

  const float FINF = __int_as_float(0x7f800000);   // +inf poison for used cols
  float2 nxtT = rowTgt[1];                         // prefetch row 1's target
  int par = 0;                                     // GLOBAL mailbox parity

  // ---- main loop over rows ----
  for (int i = 1; i <= T; ++i) {
    unsigned usedMask = 0;
    double D = 0.0;
    int i0 = i;
    double ui0 = 0.0;                // u[i] == 0 at row i's search start (R12)
    float tX = nxtT.x, tY = nxtT.y;  // prefetched during previous row's tail
    int s = 0, S;
    int j1v = 0;                         // column selected at the previous step
    int recRow = 0, recCol = 0, recPrev = 0;   // thread t records step t's state
    double recU = 0.0, recD = 0.0;
    float recTX = 0.f, recTY = 0.f;

    for (;;) {
      const int cpar = par; par ^= 1;   // global parity (uniform: lockstep)

      // record this step's pre-state on thread s (off the dependency spine)
      if (tid == s) {
        recRow = i0; recU = ui0; recTX = tX; recTY = tY; recD = D; recPrev = j1v;
      }

      // scan my 8 columns: cur = ((double)cf - u[i0]) - v[j]; used columns
      // poisoned at the f32 stage (cf = +inf => cur = +inf, never wins)
      double cv[KPT];
#pragma unroll
      for (int k = 0; k < KPT; ++k) {
        float cf = fabsf(qx[k] - tX) + fabsf(qy[k] - tY) + np_[k];
        if (usedMask & (1u << k)) cf = FINF;
        cv[k] = ((double)cf - ui0) - vreg[k];
      }
      // within-lane argmin: fmin tree for the value, then parallel ==-mask +
      // ctz => smallest k among exact equals (first occurrence; +/-0 match)
      const double m01 = fmin(cv[0], cv[1]), m23 = fmin(cv[2], cv[3]);
      const double m45 = fmin(cv[4], cv[5]), m67 = fmin(cv[6], cv[7]);
      const double m03 = fmin(m01, m23), m47 = fmin(m45, m67);
      double bval = fmin(m03, m47);
      unsigned emsk = 0;
#pragma unroll
      for (int k = 0; k < KPT; ++k) emsk |= (cv[k] == bval) ? (1u << k) : 0u;
      const int bk = (int)__builtin_ctz(emsk);   // emsk != 0 always
      int bidx = 1 + tid + (bk << 8);

      // pre-barrier: read MY candidate's colDat (this thread OWNS column
      // bidx). Off the serial chain — latency overlaps the DPP+ballot phase.
      // PADDED index: bank ~ 4*(bk+tid+1) mod 32 (bk rotates the bank group).
      const CD myCd = colDat[bidx + (bidx >> 8)];

      // monotonic u64 bit-key of the per-lane winner (canonicalize -0 -> +0)
      bval += 0.0;
      const long long bb = __double_as_longlong(bval);
      const unsigned long long key = (unsigned long long)bb ^
          ((bb < 0) ? 0xFFFFFFFFFFFFFFFFull : 0x8000000000000000ull);
      const unsigned khi = (unsigned)(key >> 32);
      const unsigned klo = (unsigned)key;

      // wave argmin: DPP min on hi32, ballot for winner, exact ties slow path
      const unsigned minhi = wave_min_u32_dpp(khi);
      const unsigned long long mask = __ballot(khi == minhi);
      int wl;
      if (__popcll(mask) == 1) {
        wl = (int)__ffsll(mask) - 1;
      } else {
        unsigned wklo = 0xffffffffu; int widx = 0x7fffffff; wl = 0;
        unsigned long long mm = mask;
        while (mm) {
          const int l = (int)__ffsll(mm) - 1; mm &= mm - 1;
          const unsigned lo2 = (unsigned)__builtin_amdgcn_readlane((int)klo, l);
          const int ix2 = __builtin_amdgcn_readlane(bidx, l);
          if (lo2 < wklo || (lo2 == wklo && ix2 < widx)) {
            wklo = lo2; widx = ix2; wl = l;
          }
        }
      }
      // the WINNING LANE writes keys + its candidate's colDat (32B, 2x b128)
      if (lane == wl) {
        pk2[cpar][wv][0] = make_uint4(minhi, klo, (unsigned)bidx, 0u);
        const unsigned long long cu =
            (unsigned long long)__double_as_longlong(myCd.u);
        pk2[cpar][wv][1] = make_uint4((unsigned)cu, (unsigned)(cu >> 32),
                                      __float_as_uint(myCd.tx),
                                      __float_as_uint(myCd.ty));
      }
      __syncthreads();            // the only per-step barrier

      // read all 8 mailbox quads — INDEPENDENT uniform broadcast reads
      const uint4 c0v = pk2[cpar][0][0];
      const uint4 c1v = pk2[cpar][1][0];
      const uint4 c2v = pk2[cpar][2][0];
      const uint4 c3v = pk2[cpar][3][0];
      const uint4 d0v = pk2[cpar][0][1];
      const uint4 d1v = pk2[cpar][1][1];
      const uint4 d2v = pk2[cpar][2][1];
      const uint4 d3v = pk2[cpar][3][1];

      // cross-wave pairwise tournament (left wins ties at every level ==
      // same winner as the left-to-right scan of R5-R15)
      const unsigned long long k0b = ((unsigned long long)c0v.x << 32) | c0v.y;
      const unsigned long long k1b = ((unsigned long long)c1v.x << 32) | c1v.y;
      const unsigned long long k2b = ((unsigned long long)c2v.x << 32) | c2v.y;
      const unsigned long long k3b = ((unsigned long long)c3v.x << 32) | c3v.y;
      const int j0b = (int)c0v.z, j1bb = (int)c1v.z;
      const int j2b = (int)c2v.z, j3b = (int)c3v.z;
      // level 1 (pairs 01 and 23, independent)
      const bool w01 = (k1b < k0b) || (k1b == k0b && j1bb < j0b);
      const unsigned long long k01 = w01 ? k1b : k0b;
      const int j01 = w01 ? j1bb : j0b;
      const bool w23 = (k3b < k2b) || (k3b == k2b && j3b < j2b);
      const unsigned long long k23 = w23 ? k3b : k2b;
      const int j23 = w23 ? j3b : j2b;
      // level 2 (final)
      const bool wf = (k23 < k01) || (k23 == k01 && j23 < j01);
      const unsigned long long bkk = wf ? k23 : k01;
      const int j1 = wf ? j23 : j01;          // selected column, 1-based
      // cd folded along the same selectors in the u32 domain (12 cndmask)
      const unsigned ulA = w01 ? d1v.x : d0v.x, uhA = w01 ? d1v.y : d0v.y;
      const unsigned xAf = w01 ? d1v.z : d0v.z, yAf = w01 ? d1v.w : d0v.w;
      const unsigned ulB = w23 ? d3v.x : d2v.x, uhB = w23 ? d3v.y : d2v.y;
      const unsigned xBf = w23 ? d3v.z : d2v.z, yBf = w23 ? d3v.w : d2v.w;
      const unsigned ulW = wf ? ulB : ulA, uhW = wf ? uhB : uhA;
      const unsigned xW = wf ? xBf : xAf, yW = wf ? yBf : yAf;
      const double cdun = __longlong_as_double(
          (long long)(((unsigned long long)uhW << 32) | ulW));
      const float cdtx = __uint_as_float(xW);
      const float cdty = __uint_as_float(yW);

      // invert bit-key -> delta (bitwise identical on every thread)
      const long long db = (long long)((bkk & 0x8000000000000000ull)
                                           ? (bkk ^ 0x8000000000000000ull) : ~bkk);
      D += __longlong_as_double(db);
      if (tid == ((j1 - 1) & 255)) usedMask |= 1u << ((j1 - 1) >> 8);
      if (tid == s) recCol = j1;
      const int pj1 = (int)p[j1];   // off-path: feeds only next step's recorder
                                    // (dead value on the final step)
      j1v = j1;
      ++s;
      if (cdtx < 0.0f) { S = s; break; }   // free column => path complete
      ui0 = cdun; tX = cdtx; tY = cdty; i0 = pj1;
    }

    // ---- row tail: NO barrier E (waves lockstep; mailbox-only post-barrier
    // reads make the epilogue's colDat/p writes race-free — R15 proof) ----
    nxtT = rowTgt[i < T ? i + 1 : T];   // prefetch next row's target (read-only)
    if (S == 1) {
      // fast path: step 0 hit a free column. unew = 0 + (D - 0) = D bitwise;
      // tX/tY still hold row i's target (state update skipped on break).
      // The column OWNER writes its own colDat + p: the only pre-barrier
      // reader of colDat[j1v] is the owner itself (same-thread ordering);
      // p[j1v] is read by others only post-next-barrier (lgkmcnt drained).
      const int c = j1v - 1;
      if (tid == (c & 255)) {
        p[j1v] = (short)i;
        CD c2; c2.u = D; c2.tx = tX; c2.ty = tY;
        colDat[j1v + (j1v >> 8)] = c2;
      }
      // no scatter slots touched; no barrier, no apply loop
    } else {
      const double Dfin = D;
      if (tid < S) {
        p[recCol] = (short)recRow;                  // augment (rows/cols distinct)
        const double unew = recU + (Dfin - recD);   // same single-add as R3-R15
        CD c2; c2.u = unew; c2.tx = recTX; c2.ty = recTY;
        colDat[recCol + (recCol >> 8)] = c2;        // refresh cache (tx >= 0)
        if (tid >= 1) {
          // column of step tid-1 (== visCol[tid]) receives Dfin - recD
          // (== Dfin - visD[tid]); path columns distinct => no collision
          vdelta[recPrev - 1] = Dfin - recD;
        }
      }
      __syncthreads();              // F: epilogue writes visible
      // owners apply their 8 slots: static indices, stride-8B conflict-free
      // reads; 0.0 slots are bitwise no-ops (x -= 0.0 == x, incl. -0.0).
#pragma unroll
      for (int k = 0; k < KPT; ++k) {
        const double dv = vdelta[tid + (k << 8)];
        vreg[k] -= dv;
        vdelta[tid + (k << 8)] = 0.0;   // reset; ordered vs next scatter by
                                        // the next row's step barriers
      }
    }
  }
  __syncthreads();

  // ---- extract assignment, rank-sort (distinct values), write int32 ----
  for (int j = 1 + tid; j <= Q; j += NT) {
    const int pi = (int)p[j];
    if (pi > 0) ansArr[pi - 1] = j - 1;
  }
  __syncthreads();
  const int a = ansArr[tid];
  int rank = 0;
  for (int t2 = 0; t2 < T; ++t2) rank += (ansArr[t2] < a) ? 1 : 0;
  out[(size_t)b * T + rank] = a;                      // row_ind (sorted query idx)
  out[(size_t)B * T + (size_t)b * T + rank] = tid;    // col_ind (target idx)
}

extern "C" void kernel_launch(void* const* d_in, const int* in_sizes, int n_in,
                              void* d_out, int out_size, void* d_ws, size_t ws_size,
                              hipStream_t stream) {
  const float* outs = (const float*)d_in[0];   // (8, 2048, 3) fp32
  const float* tgts = (const float*)d_in[1];   // (8, 256, 3) fp32
  int* out = (int*)d_out;                      // row_ind (8,256) ++ col_ind (8,256)
  hungarian_r17<<<B, NT, 0, stream>>>(outs, tgts, out);
}